// Round 1
// baseline (851.491 us; speedup 1.0000x reference)
//
#include <hip/hip_runtime.h>
#include <stdint.h>

// Shapes (fixed by the problem)
#define NBATCH 256
#define NA 196      // query rows
#define NB 196      // key/output cols
#define DK 256      // qk depth
#define DIM 1024    // value dim
// SMOOTH * log2(e)
#define SM_C 5.770780163555854f

typedef short short8 __attribute__((ext_vector_type(8)));
typedef float floatx4 __attribute__((ext_vector_type(4)));
typedef float f4 __attribute__((ext_vector_type(4)));

__device__ __forceinline__ unsigned short f32_bf16(float f) {
    unsigned u = __builtin_bit_cast(unsigned, f);
    u += 0x7fffu + ((u >> 16) & 1u);   // RNE
    return (unsigned short)(u >> 16);
}
__device__ __forceinline__ float bf16_f32(unsigned short h) {
    return __builtin_bit_cast(float, (unsigned)h << 16);
}

// -----------------------------------------------------------------------------
// Kernel 1: per batch, S^T = (Q K)^T via MFMA (hi/lo bf16 split for fp32-level
// accuracy), online row softmax (rows = a live in lane columns), write
// P^T[n][a] bf16 to workspace (a-contiguous => K-dim-contiguous for kernel 2).
// Block: 448 threads (7 waves). Wave w owns a-strip [32w, 32w+32).
// n padded to 224 (14 tiles of 16), a padded to 224 (masked at write).
// -----------------------------------------------------------------------------
__global__ __launch_bounds__(448, 1) void xattn_k1(
    const float* __restrict__ Q,        // [B][NA][DK]
    const float* __restrict__ Kg,       // [B][DK][NB]
    unsigned short* __restrict__ Pt)    // [B][NB][NA] bf16 (transposed probs)
{
    const int b = blockIdx.x;
    const float* Qb = Q + (size_t)b * NA * DK;
    const float* Kb = Kg + (size_t)b * DK * NB;
    unsigned short* Ptb = Pt + (size_t)b * NB * NA;

    // K chunk staged transposed: [n][k_local], rows padded to 40 elems (80 B,
    // 16B-aligned rows, 20-dword bank stride -> ~2-way on b128 reads = free)
    __shared__ unsigned short KtHi[224 * 40];
    __shared__ unsigned short KtLo[224 * 40];

    const int tid  = threadIdx.x;
    const int wave = tid >> 6;
    const int lane = tid & 63;
    const int q    = lane >> 4;   // quad
    const int lm   = lane & 15;

    floatx4 acc[2][14];
#pragma unroll
    for (int rt = 0; rt < 2; ++rt)
#pragma unroll
        for (int nt = 0; nt < 14; ++nt)
            acc[rt][nt] = (floatx4){0.f, 0.f, 0.f, 0.f};

    for (int kc = 0; kc < 8; ++kc) {      // 8 chunks of 32 over DK=256
        const int k0 = kc * 32;
        __syncthreads();
        // ---- stage K[k0+kk][n] -> KtHi/KtLo[n][kk] (f32 -> hi/lo bf16) ----
        for (int it = tid; it < 32 * 49; it += 448) {  // 49 float4 per k-row
            const int kk = it / 49;
            const int n4 = (it % 49) * 4;
            const f4 v = *(const f4*)(Kb + (size_t)(k0 + kk) * NB + n4);
#pragma unroll
            for (int j = 0; j < 4; ++j) {
                const float f = v[j];
                const unsigned short hi = f32_bf16(f);
                KtHi[(n4 + j) * 40 + kk] = hi;
                KtLo[(n4 + j) * 40 + kk] = f32_bf16(f - bf16_f32(hi));
            }
        }
        for (int it = tid; it < 28 * 32; it += 448) {  // zero-pad n in [196,224)
            const int n  = 196 + (it >> 5);
            const int kk = it & 31;
            KtHi[n * 40 + kk] = 0;
            KtLo[n * 40 + kk] = 0;
        }
        __syncthreads();

        // ---- Q fragments (B operand): lane = row a, 8 contiguous k ----
        short8 qHi[2], qLo[2];
#pragma unroll
        for (int rt = 0; rt < 2; ++rt) {
            int a = wave * 32 + rt * 16 + lm;
            a = a < NA ? a : NA - 1;               // clamp pad rows (masked later)
            const float* qp = Qb + (size_t)a * DK + k0 + q * 8;
            const f4 v0 = *(const f4*)qp;
            const f4 v1 = *(const f4*)(qp + 4);
#pragma unroll
            for (int j = 0; j < 8; ++j) {
                const float f = (j < 4) ? v0[j] : v1[j - 4];
                const unsigned short hi = f32_bf16(f);
                qHi[rt][j] = (short)hi;
                qLo[rt][j] = (short)f32_bf16(f - bf16_f32(hi));
            }
        }

        // ---- MFMA: D[n][a] += Kt[n][k] * Q^T[k][a], 3 products (hi/lo) ----
#pragma unroll
        for (int nt = 0; nt < 14; ++nt) {
            const short8 kHi = *(const short8*)&KtHi[(nt * 16 + lm) * 40 + q * 8];
            const short8 kLo = *(const short8*)&KtLo[(nt * 16 + lm) * 40 + q * 8];
#pragma unroll
            for (int rt = 0; rt < 2; ++rt) {
                acc[rt][nt] = __builtin_amdgcn_mfma_f32_16x16x32_bf16(kHi, qHi[rt], acc[rt][nt], 0, 0, 0);
                acc[rt][nt] = __builtin_amdgcn_mfma_f32_16x16x32_bf16(kLo, qHi[rt], acc[rt][nt], 0, 0, 0);
                acc[rt][nt] = __builtin_amdgcn_mfma_f32_16x16x32_bf16(kHi, qLo[rt], acc[rt][nt], 0, 0, 0);
            }
        }
    }

    // ---- softmax over n (per lane column a), then write P^T bf16 ----
#pragma unroll
    for (int rt = 0; rt < 2; ++rt) {
        const int a = wave * 32 + rt * 16 + lm;
        float m = -3.0e38f;
#pragma unroll
        for (int nt = 0; nt < 14; ++nt)
#pragma unroll
            for (int r = 0; r < 4; ++r) {
                const int n = nt * 16 + q * 4 + r;
                if (n < NB) m = fmaxf(m, acc[rt][nt][r]);
            }
        m = fmaxf(m, __shfl_xor(m, 16));
        m = fmaxf(m, __shfl_xor(m, 32));
        float s = 0.f;
#pragma unroll
        for (int nt = 0; nt < 14; ++nt)
#pragma unroll
            for (int r = 0; r < 4; ++r) {
                const int n = nt * 16 + q * 4 + r;
                const float p = (n < NB) ? exp2f((acc[rt][nt][r] - m) * SM_C) : 0.f;
                acc[rt][nt][r] = p;
                s += p;
            }
        s += __shfl_xor(s, 16);
        s += __shfl_xor(s, 32);
        const float inv = 1.f / s;
        if (a < NA) {
#pragma unroll
            for (int nt = 0; nt < 14; ++nt)
#pragma unroll
                for (int r = 0; r < 4; ++r) {
                    const int n = nt * 16 + q * 4 + r;
                    if (n < NB)
                        Ptb[(size_t)n * NA + a] = f32_bf16(acc[rt][nt][r] * inv);
                }
        }
    }
}

// -----------------------------------------------------------------------------
// Kernel 2: out[d][n] = sum_a V_a[d][a] * P[a][n] + V_b[d][n] + gamma.
// Block: 256 threads (4 waves), M-tile = 128 d-rows, N = all 196 (pad 224).
// A (V_a) fragments straight from global (a-contiguous rows, bf16 convert);
// B = P^T chunk staged into LDS (conflict-free, already K-contiguous).
// XCD swizzle keeps all 8 d-blocks of a batch on one XCD -> P read ~once/batch.
// -----------------------------------------------------------------------------
__global__ __launch_bounds__(256, 1) void xattn_k2(
    const float* __restrict__ Va,            // [B][DIM][NA]
    const unsigned short* __restrict__ Pt,   // [B][NB][NA] bf16
    const float* __restrict__ Vb,            // [B][DIM][NB]
    const float* __restrict__ gamma,         // [1]
    float* __restrict__ Out)                 // [B][DIM][NB]
{
    const int bid   = blockIdx.x;            // 2048 = 256 batches x 8 d-blocks
    const int batch = (bid & 7) * 32 + (bid >> 6);
    const int dblk  = (bid >> 3) & 7;

    const float* VAb = Va + (size_t)batch * DIM * NA + (size_t)dblk * 128 * NA;
    const unsigned short* Ptb = Pt + (size_t)batch * NB * NA;
    const float* VBb = Vb + (size_t)batch * DIM * NB + (size_t)dblk * 128 * NB;
    float* Ob = Out + (size_t)batch * DIM * NB + (size_t)dblk * 128 * NB;
    const float g = gamma[0];

    __shared__ unsigned short Pl[224 * 40];  // [n][a_local], rows 80 B

    const int tid  = threadIdx.x;
    const int wave = tid >> 6;
    const int lane = tid & 63;
    const int q    = lane >> 4;
    const int lm   = lane & 15;

    floatx4 acc[2][14];
#pragma unroll
    for (int rt = 0; rt < 2; ++rt)
#pragma unroll
        for (int nt = 0; nt < 14; ++nt)
            acc[rt][nt] = (floatx4){0.f, 0.f, 0.f, 0.f};

    for (int ac = 0; ac < 7; ++ac) {         // 7 chunks of 32 over a (196)
        const int a0 = ac * 32;
        __syncthreads();
        // ---- stage P^T[n][a0..a0+31] -> Pl[n][0..31] (u32, conflict-free) ----
        for (int it = tid; it < 224 * 16; it += 256) {
            const int n = it >> 4;
            const int w = it & 15;
            const int a = a0 + 2 * w;
            unsigned v = 0;
            if (n < NB && a < NA) {
                v = *(const unsigned*)(Ptb + (size_t)n * NA + a);
                if (a + 1 >= NA) v &= 0xffffu;
            }
            *(unsigned*)&Pl[n * 40 + 2 * w] = v;
        }
        __syncthreads();

        // ---- A fragments: V_a rows, 8 contiguous a, f32 -> bf16 ----
        short8 aF[2];
#pragma unroll
        for (int rt = 0; rt < 2; ++rt) {
            const int d = wave * 32 + rt * 16 + lm;     // always < 128
            const float* vp = VAb + (size_t)d * NA + a0 + q * 8;
            if (ac < 6) {
                const f4 v0 = *(const f4*)vp;
                const f4 v1 = *(const f4*)(vp + 4);
#pragma unroll
                for (int j = 0; j < 8; ++j)
                    aF[rt][j] = (short)f32_bf16((j < 4) ? v0[j] : v1[j - 4]);
            } else {
                // last chunk: per-element clamp (P padded entries are zero)
#pragma unroll
                for (int j = 0; j < 8; ++j) {
                    int a = a0 + q * 8 + j;
                    a = a < NA ? a : NA - 1;
                    aF[rt][j] = (short)f32_bf16(VAb[(size_t)d * NA + a]);
                }
            }
        }

        // ---- MFMA: D[d][n] += Va[d][a] * P[a][n] ----
#pragma unroll
        for (int nt = 0; nt < 14; ++nt) {
            const short8 bF = *(const short8*)&Pl[(nt * 16 + lm) * 40 + q * 8];
#pragma unroll
            for (int rt = 0; rt < 2; ++rt)
                acc[rt][nt] = __builtin_amdgcn_mfma_f32_16x16x32_bf16(aF[rt], bF, acc[rt][nt], 0, 0, 0);
        }
    }

    // ---- epilogue: + V_b + gamma, masked n < 196, 64 B coalesced runs ----
#pragma unroll
    for (int rt = 0; rt < 2; ++rt)
#pragma unroll
        for (int nt = 0; nt < 14; ++nt) {
            const int n = nt * 16 + lm;
            if (n < NB) {
#pragma unroll
                for (int r = 0; r < 4; ++r) {
                    const size_t off =
                        (size_t)(wave * 32 + rt * 16 + q * 4 + r) * NB + n;
                    Ob[off] = acc[rt][nt][r] + VBb[off] + g;
                }
            }
        }
}

extern "C" void kernel_launch(void* const* d_in, const int* in_sizes, int n_in,
                              void* d_out, int out_size, void* d_ws, size_t ws_size,
                              hipStream_t stream) {
    const float* Q  = (const float*)d_in[0];   // query_a [256][196][256]
    const float* VA = (const float*)d_in[1];   // value_a [256][1024][196]
    const float* KB = (const float*)d_in[2];   // key_b   [256][256][196]
    const float* VB = (const float*)d_in[3];   // value_b [256][1024][196]
    const float* GM = (const float*)d_in[4];   // gamma   [1]
    float* out = (float*)d_out;
    unsigned short* Pt = (unsigned short*)d_ws; // 256*196*196 bf16 = 19.7 MB

    xattn_k1<<<NBATCH, 448, 0, stream>>>(Q, KB, Pt);
    xattn_k2<<<NBATCH * 8, 256, 0, stream>>>(VA, Pt, VB, GM, out);
}